// Round 3
// baseline (1032.357 us; speedup 1.0000x reference)
//
#include <hip/hip_runtime.h>
#include <math.h>

typedef unsigned short u16;
typedef unsigned int u32;

typedef __attribute__((ext_vector_type(8))) short short8;
typedef __attribute__((ext_vector_type(4))) float floatx4;

#define NTILES 16384  // B*N*N/64

__device__ __forceinline__ float bfu(u16 u) { return __uint_as_float(((u32)u) << 16); }
__device__ __forceinline__ u16 f2bfs(float f) {
  u32 x = __float_as_uint(f);
  return (u16)((x + 0x7FFFu + ((x >> 16) & 1u)) >> 16);
}
// dual-dtype load: element i of buffer p, which is bf16 if b16 else fp32
__device__ __forceinline__ float ldv(const void* p, size_t i, int b16) {
  return b16 ? bfu(((const u16*)p)[i]) : ((const float*)p)[i];
}

// -------- dtype probe: adj is exactly {0.0,1.0}; fp32 words have low half 0 ----
__global__ void k_detect(const void* __restrict__ adj, int* __restrict__ flag) {
  __shared__ int found;
  if (threadIdx.x == 0) found = 0;
  __syncthreads();
  const u32* w = (const u32*)adj;
  int f = 0;
  for (int i = threadIdx.x; i < 8192; i += 256)
    if ((w[i] & 0xFFFFu) != 0u) f = 1;
  if (f) found = 1;
  __syncthreads();
  if (threadIdx.x == 0) *flag = found;
}

// ---------------- edge MLP -> e_sum [B,N,N] (the 38.7 GFLOP kernel) -------------
__global__ __launch_bounds__(256) void k_edge(const void* __restrict__ ef,
    const void* __restrict__ w1, const void* __restrict__ b1,
    const void* __restrict__ w2, const void* __restrict__ b2,
    float* __restrict__ es32, u16* __restrict__ es16, int use16,
    const int* __restrict__ flagp) {
  const int b16 = *flagp;
  __shared__ __align__(16) short T1[64 * 264];
  __shared__ __align__(16) float EF[8 * 64];
  int t = threadIdx.x;
  int lane = t & 63, w = t >> 6, q = lane >> 4, r = lane & 15;

  // ---- stage W2 (converted to bf16) transposed n-major into T1 temporarily ----
  for (int u = 0; u < 64; ++u) {
    int flat = u * 256 + t;          // flat = k*64 + n
    int k = flat >> 6, n = flat & 63;
    T1[n * 264 + k] = (short)f2bfs(ldv(w2, flat, b16));
  }
  __syncthreads();
  // ---- preload B-frags (tile-invariant): 8 k-steps x 4 n-tiles ----
  short8 bfr[8][4];
#pragma unroll
  for (int s = 0; s < 8; ++s)
#pragma unroll
    for (int nt = 0; nt < 4; ++nt)
      bfr[s][nt] = *(const short8*)(&T1[(nt * 16 + r) * 264 + s * 32 + q * 8]);
  __syncthreads();

  // per-thread layer-1 weights: column k = t of W1 [8][256]
  float w1c[8];
#pragma unroll
  for (int c = 0; c < 8; ++c) w1c[c] = ldv(w1, c * 256 + t, b16);
  float b1t = ldv(b1, t, b16);
  float b2v[4];
#pragma unroll
  for (int nt = 0; nt < 4; ++nt) b2v[nt] = ldv(b2, nt * 16 + r, b16);

  for (int tile = blockIdx.x; tile < NTILES; tile += gridDim.x) {
    // ---- stage edge features: 64 edges x 8 feats, transposed [c][m], fp32 ----
    {
      int m = t >> 2, c = (t & 3) * 2;
      size_t base = (size_t)tile * 512 + m * 8 + c;
      EF[c * 64 + m] = ldv(ef, base, b16);
      EF[(c + 1) * 64 + m] = ldv(ef, base + 1, b16);
    }
    __syncthreads();
    // ---- layer 1: thread owns output column k=t for all 64 rows ----
    for (int mt = 0; mt < 8; ++mt) {
      float acc[8];
#pragma unroll
      for (int mm = 0; mm < 8; ++mm) acc[mm] = b1t;
#pragma unroll
      for (int c = 0; c < 8; ++c) {
        const float4* ep = (const float4*)&EF[c * 64 + mt * 8];
        float4 ea = ep[0], eb = ep[1];
        float wv = w1c[c];
        acc[0] += ea.x * wv; acc[1] += ea.y * wv; acc[2] += ea.z * wv; acc[3] += ea.w * wv;
        acc[4] += eb.x * wv; acc[5] += eb.y * wv; acc[6] += eb.z * wv; acc[7] += eb.w * wv;
      }
#pragma unroll
      for (int mm = 0; mm < 8; ++mm)
        T1[(mt * 8 + mm) * 264 + t] = (short)f2bfs(tanhf(acc[mm]));
    }
    __syncthreads();
    // ---- layer 2 via MFMA 16x16x32 bf16; wave w owns rows w*16..w*16+15 ----
    floatx4 acc4[4];
#pragma unroll
    for (int nt = 0; nt < 4; ++nt) acc4[nt] = (floatx4){0.f, 0.f, 0.f, 0.f};
    const short* arow = &T1[(w * 16 + r) * 264];
#pragma unroll
    for (int s = 0; s < 8; ++s) {
      short8 af = *(const short8*)(arow + s * 32 + q * 8);
#pragma unroll
      for (int nt = 0; nt < 4; ++nt)
        acc4[nt] = __builtin_amdgcn_mfma_f32_16x16x32_bf16(af, bfr[s][nt], acc4[nt], 0, 0, 0);
    }
    // ---- epilogue: bias + tanh + row-sum over all 64 columns ----
    float s0 = 0.f, s1 = 0.f, s2 = 0.f, s3 = 0.f;
#pragma unroll
    for (int nt = 0; nt < 4; ++nt) {
      float bb = b2v[nt];
      s0 += tanhf(acc4[nt][0] + bb);
      s1 += tanhf(acc4[nt][1] + bb);
      s2 += tanhf(acc4[nt][2] + bb);
      s3 += tanhf(acc4[nt][3] + bb);
    }
#pragma unroll
    for (int off = 1; off < 16; off <<= 1) {
      s0 += __shfl_xor(s0, off, 64);
      s1 += __shfl_xor(s1, off, 64);
      s2 += __shfl_xor(s2, off, 64);
      s3 += __shfl_xor(s3, off, 64);
    }
    if (r == 0) {
      int base = tile * 64 + w * 16 + q * 4;  // C rows = q*4+reg
      if (use16) {
        es16[base] = f2bfs(s0); es16[base + 1] = f2bfs(s1);
        es16[base + 2] = f2bfs(s2); es16[base + 3] = f2bfs(s3);
      } else {
        float4 o; o.x = s0; o.y = s1; o.z = s2; o.w = s3;
        *(float4*)&es32[base] = o;
      }
    }
    __syncthreads();  // isolate iterations completely
  }
}

// ---------------- node embedding MLP: nh = tanh(tanh(nf@W1+b)@W2+b) ------------
__global__ __launch_bounds__(256) void k_node_embed(const void* __restrict__ nf,
    const void* __restrict__ w1, const void* __restrict__ b1,
    const void* __restrict__ w2, const void* __restrict__ b2,
    float* __restrict__ hid, float* __restrict__ alls,
    const int* __restrict__ flagp) {
  const int b16 = *flagp;
  __shared__ float nfx[16];
  __shared__ float t1[256];
  int node = blockIdx.x, t = threadIdx.x;
  if (t < 16) nfx[t] = ldv(nf, node * 16 + t, b16);
  __syncthreads();
  float acc = ldv(b1, t, b16);
  for (int c = 0; c < 16; ++c) acc += nfx[c] * ldv(w1, c * 256 + t, b16);
  t1[t] = tanhf(acc);
  __syncthreads();
  if (t < 64) {
    float a2 = ldv(b2, t, b16);
    for (int c = 0; c < 256; ++c) a2 += t1[c] * ldv(w2, c * 64 + t, b16);
    float v = tanhf(a2);
    hid[node * 64 + t] = v;
    alls[node * 256 + t] = v;
  }
}

// ---------------- dinv[b,i] = 1/(rowsum(adj)+1) -------------------------------
__global__ __launch_bounds__(256) void k_dinv(const void* __restrict__ adj,
    float* __restrict__ dinv, const int* __restrict__ flagp) {
  const int b16 = *flagp;
  int t = threadIdx.x, lane = t & 63;
  int row = blockIdx.x * 4 + (t >> 6);
  float s = 0.f;
#pragma unroll
  for (int u = 0; u < 8; ++u) s += ldv(adj, (size_t)row * 512 + u * 64 + lane, b16);
#pragma unroll
  for (int off = 32; off > 0; off >>= 1) s += __shfl_xor(s, off, 64);
  if (lane == 0) dinv[row] = 1.0f / (s + 1.0f);
}

// ---------------- tmp = hidden @ gcn_w[l] -------------------------------------
__global__ __launch_bounds__(256) void k_gcn_tmp(const float* __restrict__ hid,
    const void* __restrict__ gw, float* __restrict__ tmp, int l,
    const int* __restrict__ flagp) {
  const int b16 = *flagp;
  __shared__ float hr[256];
  int t = threadIdx.x;
  int node0 = blockIdx.x * 4;
  hr[t] = hid[node0 * 64 + t];
  __syncthreads();
  int nl = t >> 6, h = t & 63;
  float acc = 0.f;
  for (int c = 0; c < 64; ++c) acc += hr[nl * 64 + c] * ldv(gw, l * 4096 + c * 64 + h, b16);
  tmp[(node0 + nl) * 64 + h] = acc;
}

// ------- adjacency-style matmul: out = tanh(scale * A @ X), 8 rows/block ------
// MODE 0: A=adj, scale=dinv, X=tmp, out=hidden, also emits vn partial sums
// MODE 1: A=e_sum(fp32 or bf16 internal), X=hidden+vn, out=gated
template <int MODE>
__global__ __launch_bounds__(256) void k_adjmm(const void* __restrict__ adj,
    const float* __restrict__ es32, const u16* __restrict__ es16, int use16,
    const float* __restrict__ X,
    const float* __restrict__ vn, const float* __restrict__ dinv,
    float* __restrict__ out, float* __restrict__ vnpart,
    const int* __restrict__ flagp) {
  const int b16 = *flagp;
  __shared__ float Xt[64 * 64];
  __shared__ float Al[8 * 64];
  __shared__ float red[256];
  int t = threadIdx.x;
  int b = blockIdx.x >> 6, it = blockIdx.x & 63;
  int h = t & 63, ig = t >> 6;
  float acc0 = 0.f, acc1 = 0.f;
  for (int jt = 0; jt < 8; ++jt) {
    __syncthreads();
    for (int u = 0; u < 16; ++u) {
      int idx = u * 256 + t;
      int jl = idx >> 6, hh = idx & 63;
      float xv = X[(b * 512 + jt * 64 + jl) * 64 + hh];
      if (MODE) xv += vn[b * 64 + hh];
      Xt[idx] = xv;
    }
#pragma unroll
    for (int u = 0; u < 2; ++u) {
      int idx = u * 256 + t;
      int il = idx >> 6, jl = idx & 63;
      size_t ai = ((size_t)(b * 512 + it * 8 + il)) * 512 + jt * 64 + jl;
      float av;
      if (MODE) av = use16 ? bfu(es16[ai]) : es32[ai];
      else      av = ldv(adj, ai, b16);
      Al[idx] = av;
    }
    __syncthreads();
    int i0 = ig * 2;
    for (int jl = 0; jl < 64; ++jl) {
      float xv = Xt[jl * 64 + h];
      acc0 += Al[i0 * 64 + jl] * xv;
      acc1 += Al[i0 * 64 + 64 + jl] * xv;
    }
  }
  int gi = b * 512 + it * 8 + ig * 2;
  float o0, o1;
  if (MODE) { o0 = tanhf(acc0); o1 = tanhf(acc1); }
  else { o0 = tanhf(acc0 * dinv[gi]); o1 = tanhf(acc1 * dinv[gi + 1]); }
  out[gi * 64 + h] = o0;
  out[(gi + 1) * 64 + h] = o1;
  if (!MODE) {
    red[t] = o0 + o1;
    __syncthreads();
    if (t < 64) {
      float s = red[t] + red[t + 64] + red[t + 128] + red[t + 192];
      vnpart[(b * 64 + it) * 64 + t] = s;
    }
  }
}

// ---------------- virtual-node MLP with BatchNorm over batch-of-4 -------------
__global__ __launch_bounds__(256) void k_vn_mlp(const float* __restrict__ vnpart,
    const void* __restrict__ w1, const void* __restrict__ bb1,
    const void* __restrict__ g1, const void* __restrict__ be1,
    const void* __restrict__ w2, const void* __restrict__ bb2,
    const void* __restrict__ g2, const void* __restrict__ be2,
    float* __restrict__ vn, int l, const int* __restrict__ flagp) {
  const int b16 = *flagp;
  __shared__ float x0[256], x1[512], y1[512], x2[256];
  int t = threadIdx.x;
  {
    int b = t >> 6, h = t & 63;
    float s = 0.f;
    for (int c = 0; c < 64; ++c) s += vnpart[(b * 64 + c) * 64 + h];
    x0[t] = s * (1.0f / 512.0f);
  }
  __syncthreads();
  for (int rep = 0; rep < 2; ++rep) {
    int idx = rep * 256 + t;
    int b = idx >> 7, j = idx & 127;
    float acc = ldv(bb1, l * 128 + j, b16);
    for (int h = 0; h < 64; ++h) acc += x0[b * 64 + h] * ldv(w1, l * 8192 + h * 128 + j, b16);
    x1[idx] = acc;
  }
  __syncthreads();
  if (t < 128) {
    int j = t;
    float a = x1[j], bq = x1[128 + j], c = x1[256 + j], d = x1[384 + j];
    float m = 0.25f * (a + bq + c + d);
    float da = a - m, db = bq - m, dc = c - m, dd = d - m;
    float var = 0.25f * (da * da + db * db + dc * dc + dd * dd);
    float sc = ldv(g1, l * 128 + j, b16) / sqrtf(var + 1e-5f);
    float be = ldv(be1, l * 128 + j, b16);
    y1[j]       = fmaxf(sc * da + be, 0.f);
    y1[128 + j] = fmaxf(sc * db + be, 0.f);
    y1[256 + j] = fmaxf(sc * dc + be, 0.f);
    y1[384 + j] = fmaxf(sc * dd + be, 0.f);
  }
  __syncthreads();
  {
    int b = t >> 6, k = t & 63;
    float acc = ldv(bb2, l * 64 + k, b16);
    for (int j = 0; j < 128; ++j) acc += y1[b * 128 + j] * ldv(w2, l * 8192 + j * 64 + k, b16);
    x2[t] = acc;
  }
  __syncthreads();
  if (t < 64) {
    int k = t;
    float a = x2[k], bq = x2[64 + k], c = x2[128 + k], d = x2[192 + k];
    float m = 0.25f * (a + bq + c + d);
    float da = a - m, db = bq - m, dc = c - m, dd = d - m;
    float var = 0.25f * (da * da + db * db + dc * dc + dd * dd);
    float sc = ldv(g2, l * 64 + k, b16) / sqrtf(var + 1e-5f);
    float be = ldv(be2, l * 64 + k, b16);
    vn[k]       = fmaxf(sc * da + be, 0.f);
    vn[64 + k]  = fmaxf(sc * db + be, 0.f);
    vn[128 + k] = fmaxf(sc * dc + be, 0.f);
    vn[192 + k] = fmaxf(sc * dd + be, 0.f);
  }
}

// -------- hidden = tanh(concat(hidden+vn, gated) @ comb_w + comb_b) -----------
__global__ __launch_bounds__(256) void k_comb(const float* hid,
    const float* __restrict__ gated, const float* __restrict__ vn,
    const void* __restrict__ cw, const void* __restrict__ cb,
    float* hidout, float* __restrict__ alls, int l,
    const int* __restrict__ flagp) {
  const int b16 = *flagp;
  __shared__ float cat[4 * 128];
  int t = threadIdx.x;
  int node0 = blockIdx.x * 4;
#pragma unroll
  for (int u = 0; u < 2; ++u) {
    int idx = u * 256 + t;
    int nl = idx >> 7, c = idx & 127;
    int node = node0 + nl;
    int b = node >> 9;
    float v;
    if (c < 64) v = hid[node * 64 + c] + vn[b * 64 + c];
    else        v = gated[node * 64 + (c - 64)];
    cat[idx] = v;
  }
  __syncthreads();
  int nl = t >> 6, h = t & 63;
  float acc = ldv(cb, l * 64 + h, b16);
  for (int c = 0; c < 128; ++c) acc += cat[nl * 128 + c] * ldv(cw, l * 8192 + c * 64 + h, b16);
  float v = tanhf(acc);
  int node = node0 + nl;
  hidout[node * 64 + h] = v;
  alls[node * 256 + (l + 1) * 64 + h] = v;
}

// -------- latent MLP per node + partial lat_sum over 8-node chunks ------------
__global__ __launch_bounds__(256) void k_lat(const float* __restrict__ alls,
    const void* __restrict__ w1, const void* __restrict__ bb1,
    const void* __restrict__ w2, const void* __restrict__ bb2,
    float* __restrict__ latpart, const int* __restrict__ flagp) {
  const int b16 = *flagp;
  __shared__ float x[256], t1[256];
  int t = threadIdx.x;
  int b = blockIdx.x >> 6, chunk = blockIdx.x & 63;
  float acc2 = 0.f;
  for (int u = 0; u < 8; ++u) {
    int node = b * 512 + chunk * 8 + u;
    x[t] = alls[node * 256 + t];
    __syncthreads();
    float a1 = ldv(bb1, t, b16);
    for (int c = 0; c < 256; ++c) a1 += x[c] * ldv(w1, c * 256 + t, b16);
    t1[t] = tanhf(a1);
    __syncthreads();
    if (t < 64) {
      float a2 = ldv(bb2, t, b16);
      for (int c = 0; c < 256; ++c) a2 += t1[c] * ldv(w2, c * 64 + t, b16);
      acc2 += tanhf(a2);
    }
    __syncthreads();
  }
  if (t < 64) latpart[(b * 64 + chunk) * 64 + t] = acc2;
}

// -------- combine lat_sum, write it, FC head, write predict -------------------
__global__ __launch_bounds__(256) void k_final(const float* __restrict__ latpart,
    const void* __restrict__ f1w, const void* __restrict__ f1b,
    const void* __restrict__ f2w, const void* __restrict__ f2b,
    void* __restrict__ outp, const int* __restrict__ flagp) {
  const int b16 = *flagp;
  __shared__ float ls[256];
  __shared__ float hb[2048];
  int t = threadIdx.x;
  {
    int b = t >> 6, z = t & 63;
    float s = 0.f;
    for (int c = 0; c < 64; ++c) s += latpart[(b * 64 + c) * 64 + z];
    ls[t] = s;
    if (b16) ((u16*)outp)[4 + t] = f2bfs(s);
    else     ((float*)outp)[4 + t] = s;        // lat_sum output
  }
  __syncthreads();
  for (int rep = 0; rep < 8; ++rep) {
    int idx = rep * 256 + t;
    int b = idx >> 9, k = idx & 511;
    float acc = ldv(f1b, k, b16);
    for (int z = 0; z < 64; ++z) acc += ls[b * 64 + z] * ldv(f1w, z * 512 + k, b16);
    hb[idx] = tanhf(acc);
  }
  __syncthreads();
  {
    int b = t >> 6, lane = t & 63;
    float acc = 0.f;
#pragma unroll
    for (int u = 0; u < 8; ++u) acc += hb[b * 512 + lane + u * 64] * ldv(f2w, lane + u * 64, b16);
#pragma unroll
    for (int off = 32; off > 0; off >>= 1) acc += __shfl_xor(acc, off, 64);
    if (lane == 0) {
      float pv = acc + ldv(f2b, 0, b16);
      if (b16) ((u16*)outp)[b] = f2bfs(pv);
      else     ((float*)outp)[b] = pv;         // predict output
    }
  }
}

extern "C" void kernel_launch(void* const* d_in, const int* in_sizes, int n_in,
                              void* d_out, int out_size, void* d_ws, size_t ws_size,
                              hipStream_t stream) {
  const void* adj       = d_in[0];
  const void* node_feat = d_in[1];
  const void* edge_feat = d_in[2];
  const void* nf1_w = d_in[3];
  const void* nf1_b = d_in[4];
  const void* nf2_w = d_in[5];
  const void* nf2_b = d_in[6];
  const void* ef1_w = d_in[7];
  const void* ef1_b = d_in[8];
  const void* ef2_w = d_in[9];
  const void* ef2_b = d_in[10];
  const void* gcn_w = d_in[11];
  const void* vn1_w = d_in[12];
  const void* vn1_b = d_in[13];
  const void* vn1_g = d_in[14];
  const void* vn1_be = d_in[15];
  const void* vn2_w = d_in[16];
  const void* vn2_b = d_in[17];
  const void* vn2_g = d_in[18];
  const void* vn2_be = d_in[19];
  const void* comb_w = d_in[20];
  const void* comb_b = d_in[21];
  const void* lat1_w = d_in[22];
  const void* lat1_b = d_in[23];
  const void* lat2_w = d_in[24];
  const void* lat2_b = d_in[25];
  const void* fc1_w = d_in[26];
  const void* fc1_b = d_in[27];
  const void* fc2_w = d_in[28];
  const void* fc2_b = d_in[29];

  // ---- workspace layout, chosen by ws_size (deterministic across calls) ----
  const int use16 = (ws_size < (size_t)12 * 1024 * 1024) ? 1 : 0;
  char* p = (char*)d_ws;
  float* es32 = (float*)p;
  u16*   es16 = (u16*)p;
  size_t es_bytes = use16 ? (size_t)1048576 * 2 : (size_t)1048576 * 4;
  float* alls    = (float*)(p + es_bytes);  // 524288 floats
  float* hid     = alls + 524288;           // 131072
  float* tmp     = hid + 131072;            // 131072 (gcn tmp, then gated)
  float* dinv    = tmp + 131072;            // 2048
  float* vnpart  = dinv + 2048;             // 16384
  float* vn      = vnpart + 16384;          // 256
  float* latpart = vn + 256;                // 16384
  int*   flag    = (int*)(latpart + 16384); // 1

  k_detect<<<1, 256, 0, stream>>>(adj, flag);
  k_edge<<<1024, 256, 0, stream>>>(edge_feat, ef1_w, ef1_b, ef2_w, ef2_b,
                                   es32, es16, use16, flag);
  k_node_embed<<<2048, 256, 0, stream>>>(node_feat, nf1_w, nf1_b, nf2_w, nf2_b,
                                         hid, alls, flag);
  k_dinv<<<512, 256, 0, stream>>>(adj, dinv, flag);
  for (int l = 0; l < 3; ++l) {
    k_gcn_tmp<<<512, 256, 0, stream>>>(hid, gcn_w, tmp, l, flag);
    k_adjmm<0><<<256, 256, 0, stream>>>(adj, es32, es16, use16, tmp, vn, dinv,
                                        hid, vnpart, flag);
    k_vn_mlp<<<1, 256, 0, stream>>>(vnpart, vn1_w, vn1_b, vn1_g, vn1_be,
                                    vn2_w, vn2_b, vn2_g, vn2_be, vn, l, flag);
    k_adjmm<1><<<256, 256, 0, stream>>>(adj, es32, es16, use16, hid, vn, dinv,
                                        tmp, vnpart, flag);
    k_comb<<<512, 256, 0, stream>>>(hid, tmp, vn, comb_w, comb_b, hid, alls, l, flag);
  }
  k_lat<<<256, 256, 0, stream>>>(alls, lat1_w, lat1_b, lat2_w, lat2_b, latpart, flag);
  k_final<<<1, 256, 0, stream>>>(latpart, fc1_w, fc1_b, fc2_w, fc2_b, d_out, flag);
}

// Round 5
// 536.890 us; speedup vs baseline: 1.9228x; 1.9228x over previous
//
#include <hip/hip_runtime.h>
#include <math.h>

typedef unsigned short u16;
typedef unsigned int u32;

typedef __attribute__((ext_vector_type(8))) short short8;
typedef __attribute__((ext_vector_type(4))) float floatx4;

#define NTILES 16384  // B*N*N/64

__device__ __forceinline__ float bfu(u16 u) { return __uint_as_float(((u32)u) << 16); }
__device__ __forceinline__ u16 f2bfs(float f) {
  u32 x = __float_as_uint(f);
  return (u16)((x + 0x7FFFu + ((x >> 16) & 1u)) >> 16);
}
__device__ __forceinline__ float tanh_fast(float x) {
  // tanh(x) = 1 - 2/(exp2(2*log2e*x)+1); exact saturation, ~1e-6 abs err
  float e = __builtin_amdgcn_exp2f(x * 2.885390081777927f);
  return 1.0f - 2.0f * __builtin_amdgcn_rcpf(e + 1.0f);
}

// ---------------- edge MLP -> e_sum [B,N,N] (the 38.7 GFLOP kernel) -----------
__global__ __launch_bounds__(256) void k_edge(const float* __restrict__ ef,
    const float* __restrict__ w1, const float* __restrict__ b1,
    const float* __restrict__ w2, const float* __restrict__ b2,
    float* __restrict__ es32, u16* __restrict__ es16, int use16) {
  __shared__ __align__(16) short T1[64 * 264];
  __shared__ __align__(16) float EF[8 * 64];
  int t = threadIdx.x;
  int lane = t & 63, w = t >> 6, q = lane >> 4, r = lane & 15;

  // stage W2 (bf16-converted) transposed n-major into T1 temporarily
  for (int u = 0; u < 64; ++u) {
    int flat = u * 256 + t;          // flat = k*64 + n
    int k = flat >> 6, n = flat & 63;
    T1[n * 264 + k] = (short)f2bfs(w2[flat]);
  }
  __syncthreads();
  short8 bfr[8][4];
#pragma unroll
  for (int s = 0; s < 8; ++s)
#pragma unroll
    for (int nt = 0; nt < 4; ++nt)
      bfr[s][nt] = *(const short8*)(&T1[(nt * 16 + r) * 264 + s * 32 + q * 8]);
  __syncthreads();

  float w1c[8];
#pragma unroll
  for (int c = 0; c < 8; ++c) w1c[c] = w1[c * 256 + t];
  float b1t = b1[t];
  float b2v[4];
#pragma unroll
  for (int nt = 0; nt < 4; ++nt) b2v[nt] = b2[nt * 16 + r];

  for (int tile = blockIdx.x; tile < NTILES; tile += gridDim.x) {
    {
      int m = t >> 2, c = (t & 3) * 2;
      float2 e2 = *(const float2*)(ef + (size_t)tile * 512 + m * 8 + c);
      EF[c * 64 + m] = e2.x;
      EF[(c + 1) * 64 + m] = e2.y;
    }
    __syncthreads();
    for (int mt = 0; mt < 8; ++mt) {
      float acc[8];
#pragma unroll
      for (int mm = 0; mm < 8; ++mm) acc[mm] = b1t;
#pragma unroll
      for (int c = 0; c < 8; ++c) {
        const float4* ep = (const float4*)&EF[c * 64 + mt * 8];
        float4 ea = ep[0], eb = ep[1];
        float wv = w1c[c];
        acc[0] += ea.x * wv; acc[1] += ea.y * wv; acc[2] += ea.z * wv; acc[3] += ea.w * wv;
        acc[4] += eb.x * wv; acc[5] += eb.y * wv; acc[6] += eb.z * wv; acc[7] += eb.w * wv;
      }
#pragma unroll
      for (int mm = 0; mm < 8; ++mm)
        T1[(mt * 8 + mm) * 264 + t] = (short)f2bfs(tanh_fast(acc[mm]));
    }
    __syncthreads();
    floatx4 acc4[4];
#pragma unroll
    for (int nt = 0; nt < 4; ++nt) acc4[nt] = (floatx4){0.f, 0.f, 0.f, 0.f};
    const short* arow = &T1[(w * 16 + r) * 264];
#pragma unroll
    for (int s = 0; s < 8; ++s) {
      short8 af = *(const short8*)(arow + s * 32 + q * 8);
#pragma unroll
      for (int nt = 0; nt < 4; ++nt)
        acc4[nt] = __builtin_amdgcn_mfma_f32_16x16x32_bf16(af, bfr[s][nt], acc4[nt], 0, 0, 0);
    }
    float s0 = 0.f, s1 = 0.f, s2 = 0.f, s3 = 0.f;
#pragma unroll
    for (int nt = 0; nt < 4; ++nt) {
      float bb = b2v[nt];
      s0 += tanh_fast(acc4[nt][0] + bb);
      s1 += tanh_fast(acc4[nt][1] + bb);
      s2 += tanh_fast(acc4[nt][2] + bb);
      s3 += tanh_fast(acc4[nt][3] + bb);
    }
#pragma unroll
    for (int off = 1; off < 16; off <<= 1) {
      s0 += __shfl_xor(s0, off, 64);
      s1 += __shfl_xor(s1, off, 64);
      s2 += __shfl_xor(s2, off, 64);
      s3 += __shfl_xor(s3, off, 64);
    }
    if (r == 0) {
      int base = tile * 64 + w * 16 + q * 4;  // C rows = q*4+reg
      if (use16) {
        es16[base] = f2bfs(s0); es16[base + 1] = f2bfs(s1);
        es16[base + 2] = f2bfs(s2); es16[base + 3] = f2bfs(s3);
      } else {
        float4 o; o.x = s0; o.y = s1; o.z = s2; o.w = s3;
        *(float4*)&es32[base] = o;
      }
    }
    __syncthreads();  // REQUIRED: EF restage vs layer-1 EF reads of prev tile
  }
}

// -------- node embedding MLP + gcn_tmp(l=0), 4 nodes/block --------------------
__global__ __launch_bounds__(256) void k_node_gcn(const float* __restrict__ nf,
    const float* __restrict__ w1, const float* __restrict__ b1,
    const float* __restrict__ w2, const float* __restrict__ b2,
    const float* __restrict__ gw,
    float* __restrict__ hid, u16* __restrict__ alls16, float* __restrict__ tmp) {
  __shared__ float nfx[4][16];
  __shared__ float t1[4][256];
  __shared__ float nh[4][64];
  int t = threadIdx.x;
  int node0 = blockIdx.x * 4;
  if (t < 64) nfx[t >> 4][t & 15] = nf[node0 * 16 + t];
  __syncthreads();
  float b1t = b1[t];
  float a0 = b1t, a1 = b1t, a2 = b1t, a3 = b1t;
#pragma unroll
  for (int c = 0; c < 16; ++c) {
    float wv = w1[c * 256 + t];
    a0 += nfx[0][c] * wv; a1 += nfx[1][c] * wv;
    a2 += nfx[2][c] * wv; a3 += nfx[3][c] * wv;
  }
  t1[0][t] = tanh_fast(a0); t1[1][t] = tanh_fast(a1);
  t1[2][t] = tanh_fast(a2); t1[3][t] = tanh_fast(a3);
  __syncthreads();
  int nl = t >> 6, h = t & 63;
  {
    float acc = b2[h];
    for (int c = 0; c < 256; c += 4) {
      float4 xv = *(const float4*)&t1[nl][c];
      acc += xv.x * w2[c * 64 + h] + xv.y * w2[(c + 1) * 64 + h]
           + xv.z * w2[(c + 2) * 64 + h] + xv.w * w2[(c + 3) * 64 + h];
    }
    float v = tanh_fast(acc);
    int node = node0 + nl;
    hid[node * 64 + h] = v;
    alls16[node * 256 + h] = f2bfs(v);
    nh[nl][h] = v;
  }
  __syncthreads();
  {
    float g = 0.f;
    for (int c = 0; c < 64; ++c) g += nh[nl][c] * gw[c * 64 + h];
    tmp[(node0 + nl) * 64 + h] = g;
  }
}

// ---------------- dinv + zero the layer counters ------------------------------
__global__ __launch_bounds__(256) void k_dinv(const float* __restrict__ adj,
    float* __restrict__ dinv, int* __restrict__ cnt) {
  int t = threadIdx.x, lane = t & 63;
  if (blockIdx.x == 0 && t < 4) cnt[t] = 0;
  int row = blockIdx.x * 4 + (t >> 6);
  float s = 0.f;
#pragma unroll
  for (int u = 0; u < 8; ++u) s += adj[(size_t)row * 512 + u * 64 + lane];
#pragma unroll
  for (int off = 32; off > 0; off >>= 1) s += __shfl_xor(s, off, 64);
  if (lane == 0) dinv[row] = 1.0f / (s + 1.0f);
}

// ------- adjacency-style matmul: out = tanh(scale * A @ X), 8 rows/block ------
// MODE 0: A=adj, scale=dinv, X=tmp, out=hidden, + vn partials + fused vn_mlp
// MODE 1: A=e_sum, X=hidden+vn, out=gated
template <int MODE>
__global__ __launch_bounds__(256) void k_adjmm(const float* __restrict__ adj,
    const float* __restrict__ es32, const u16* __restrict__ es16, int use16,
    const float* __restrict__ X, const float* __restrict__ vnin,
    const float* __restrict__ dinv,
    float* __restrict__ out, float* __restrict__ vnpart, int* cnt,
    const float* __restrict__ vw1, const float* __restrict__ vb1,
    const float* __restrict__ vg1, const float* __restrict__ vbe1,
    const float* __restrict__ vw2, const float* __restrict__ vb2,
    const float* __restrict__ vg2, const float* __restrict__ vbe2,
    float* __restrict__ vnout, int l) {
  __shared__ float Xt[64 * 64];
  __shared__ float Al[8 * 65];
  __shared__ floatx4 red4[256];
  __shared__ int isLast;
  int t = threadIdx.x;
  int b = blockIdx.x >> 6, it = blockIdx.x & 63;
  int hq = t & 15, slot = t >> 4, row = slot & 7, half = slot >> 3;
  floatx4 acc = (floatx4){0.f, 0.f, 0.f, 0.f};
  for (int jt = 0; jt < 8; ++jt) {
    __syncthreads();
    for (int u = 0; u < 16; ++u) {
      int idx = u * 256 + t;
      int jl = idx >> 6, hh = idx & 63;
      float xv = X[(b * 512 + jt * 64 + jl) * 64 + hh];
      if (MODE) xv += vnin[b * 64 + hh];
      Xt[idx] = xv;
    }
#pragma unroll
    for (int u = 0; u < 2; ++u) {
      int idx = u * 256 + t;
      int il = idx >> 6, jl = idx & 63;
      size_t ai = ((size_t)(b * 512 + it * 8 + il)) * 512 + jt * 64 + jl;
      float av;
      if (MODE) av = use16 ? bfu(es16[ai]) : es32[ai];
      else      av = adj[ai];
      Al[il * 65 + jl] = av;
    }
    __syncthreads();
    const float* xp = &Xt[(half * 32) * 64 + hq * 4];
    const float* ap = &Al[row * 65 + half * 32];
#pragma unroll
    for (int jl = 0; jl < 32; ++jl) {
      floatx4 xv = *(const floatx4*)(xp + jl * 64);
      float a = ap[jl];
      acc[0] += a * xv[0]; acc[1] += a * xv[1];
      acc[2] += a * xv[2]; acc[3] += a * xv[3];
    }
  }
  red4[t] = acc;
  __syncthreads();
  if (t < 128) {   // slot = row (half 0); pair at t+128 is half 1
    floatx4 s = red4[t], s2 = red4[t + 128];
    int gr = b * 512 + it * 8 + row;
    floatx4 o;
    if (MODE) {
#pragma unroll
      for (int i = 0; i < 4; ++i) o[i] = tanh_fast(s[i] + s2[i]);
    } else {
      float d = dinv[gr];
#pragma unroll
      for (int i = 0; i < 4; ++i) o[i] = tanh_fast((s[i] + s2[i]) * d);
    }
    *(floatx4*)&out[gr * 64 + hq * 4] = o;
    if (!MODE) red4[t] = o;
  }
  if (!MODE) {
    __syncthreads();
    if (t < 16) {
      floatx4 ssum = (floatx4){0.f, 0.f, 0.f, 0.f};
#pragma unroll
      for (int r2 = 0; r2 < 8; ++r2) {
        floatx4 v = red4[r2 * 16 + t];
        ssum[0] += v[0]; ssum[1] += v[1]; ssum[2] += v[2]; ssum[3] += v[3];
      }
      *(floatx4*)&vnpart[(b * 64 + it) * 64 + t * 4] = ssum;
    }
    __threadfence();
    __syncthreads();
    if (t == 0) isLast = (atomicAdd(cnt, 1) == 255);
    __syncthreads();
    if (isLast) {
      __threadfence();
      // ---- fused virtual-node MLP with BatchNorm over batch-of-4 ----
      float* x0 = Xt; float* x1 = Xt + 256; float* y1 = Xt + 768; float* x2 = Xt + 1280;
      {
        int bb = t >> 6, h = t & 63;
        float s = 0.f;
        for (int c = 0; c < 64; ++c) s += vnpart[(bb * 64 + c) * 64 + h];
        x0[t] = s * (1.0f / 512.0f);
      }
      __syncthreads();
      for (int rep = 0; rep < 2; ++rep) {
        int idx = rep * 256 + t;
        int bb = idx >> 7, j = idx & 127;
        float a = vb1[l * 128 + j];
        for (int h = 0; h < 64; ++h) a += x0[bb * 64 + h] * vw1[l * 8192 + h * 128 + j];
        x1[idx] = a;
      }
      __syncthreads();
      if (t < 128) {
        int j = t;
        float a = x1[j], bq = x1[128 + j], c = x1[256 + j], d = x1[384 + j];
        float m = 0.25f * (a + bq + c + d);
        float da = a - m, db = bq - m, dc = c - m, dd = d - m;
        float var = 0.25f * (da * da + db * db + dc * dc + dd * dd);
        float sc = vg1[l * 128 + j] / sqrtf(var + 1e-5f);
        float be = vbe1[l * 128 + j];
        y1[j]       = fmaxf(sc * da + be, 0.f);
        y1[128 + j] = fmaxf(sc * db + be, 0.f);
        y1[256 + j] = fmaxf(sc * dc + be, 0.f);
        y1[384 + j] = fmaxf(sc * dd + be, 0.f);
      }
      __syncthreads();
      {
        int bb = t >> 6, k = t & 63;
        float a = vb2[l * 64 + k];
        for (int j = 0; j < 128; ++j) a += y1[bb * 128 + j] * vw2[l * 8192 + j * 64 + k];
        x2[t] = a;
      }
      __syncthreads();
      if (t < 64) {
        int k = t;
        float a = x2[k], bq = x2[64 + k], c = x2[128 + k], d = x2[192 + k];
        float m = 0.25f * (a + bq + c + d);
        float da = a - m, db = bq - m, dc = c - m, dd = d - m;
        float var = 0.25f * (da * da + db * db + dc * dc + dd * dd);
        float sc = vg2[l * 64 + k] / sqrtf(var + 1e-5f);
        float be = vbe2[l * 64 + k];
        vnout[k]       = fmaxf(sc * da + be, 0.f);
        vnout[64 + k]  = fmaxf(sc * db + be, 0.f);
        vnout[128 + k] = fmaxf(sc * dc + be, 0.f);
        vnout[192 + k] = fmaxf(sc * dd + be, 0.f);
      }
    }
  }
}

// -------- comb (+ fused gcn_tmp for next layer), 4 nodes/block ----------------
__global__ __launch_bounds__(256) void k_comb_gcn(const float* hid,
    const float* gated, const float* __restrict__ vn,
    const float* __restrict__ cw, const float* __restrict__ cb,
    const float* __restrict__ gw_next,
    u16* __restrict__ alls16, float* tmpout, int l, int do_gcn) {
  __shared__ float cat[4 * 128];
  __shared__ float nh[4][64];
  int t = threadIdx.x;
  int node0 = blockIdx.x * 4;
#pragma unroll
  for (int u = 0; u < 2; ++u) {
    int idx = u * 256 + t;
    int nl = idx >> 7, c = idx & 127;
    int node = node0 + nl;
    int b = node >> 9;
    float v;
    if (c < 64) v = hid[node * 64 + c] + vn[b * 64 + c];
    else        v = gated[node * 64 + (c - 64)];
    cat[idx] = v;
  }
  __syncthreads();
  int nl = t >> 6, h = t & 63;
  float acc = cb[l * 64 + h];
  const float* wp = cw + l * 8192 + h;
  for (int c = 0; c < 128; c += 4) {
    float4 xv = *(const float4*)&cat[nl * 128 + c];
    acc += xv.x * wp[c * 64] + xv.y * wp[(c + 1) * 64]
         + xv.z * wp[(c + 2) * 64] + xv.w * wp[(c + 3) * 64];
  }
  float v = tanh_fast(acc);
  int node = node0 + nl;
  ((float*)hid)[node * 64 + h] = v;   // in-place update (block-local rows)
  alls16[node * 256 + (l + 1) * 64 + h] = f2bfs(v);
  if (do_gcn) {
    nh[nl][h] = v;
    __syncthreads();
    float g = 0.f;
    for (int c = 0; c < 64; ++c) g += nh[nl][c] * gw_next[c * 64 + h];
    tmpout[node * 64 + h] = g;
  }
}

// -------- latent MLP, 8 nodes/block batched + partial lat_sum -----------------
__global__ __launch_bounds__(256) void k_lat(const u16* __restrict__ alls16,
    const float* __restrict__ w1, const float* __restrict__ bb1,
    const float* __restrict__ w2, const float* __restrict__ bb2,
    float* __restrict__ latpart) {
  __shared__ float x[8][256];
  __shared__ float t1[8][256];
  __shared__ float red[8][256];
  int t = threadIdx.x;
  int b = blockIdx.x >> 6, chunk = blockIdx.x & 63;
#pragma unroll
  for (int u = 0; u < 8; ++u)
    x[u][t] = bfu(alls16[(size_t)(b * 512 + chunk * 8 + u) * 256 + t]);
  __syncthreads();
  float a1[8];
  float bb = bb1[t];
#pragma unroll
  for (int u = 0; u < 8; ++u) a1[u] = bb;
  for (int c = 0; c < 256; ++c) {
    float wv = w1[c * 256 + t];
#pragma unroll
    for (int u = 0; u < 8; ++u) a1[u] += x[u][c] * wv;
  }
#pragma unroll
  for (int u = 0; u < 8; ++u) t1[u][t] = tanh_fast(a1[u]);
  __syncthreads();
  int quar = t >> 6, k = t & 63, c0 = quar * 64;
  float a2[8];
#pragma unroll
  for (int u = 0; u < 8; ++u) a2[u] = 0.f;
  for (int c = 0; c < 64; ++c) {
    float wv = w2[(c0 + c) * 64 + k];
#pragma unroll
    for (int u = 0; u < 8; ++u) a2[u] += t1[u][c0 + c] * wv;
  }
#pragma unroll
  for (int u = 0; u < 8; ++u) red[u][t] = a2[u];
  __syncthreads();
  if (t < 64) {
    float acc2 = 0.f;
    float b2v = bb2[t];
#pragma unroll
    for (int u = 0; u < 8; ++u) {
      float s = red[u][t] + red[u][t + 64] + red[u][t + 128] + red[u][t + 192] + b2v;
      acc2 += tanh_fast(s);
    }
    latpart[(b * 64 + chunk) * 64 + t] = acc2;
  }
}

// -------- combine lat_sum, write it, FC head, write predict -------------------
__global__ __launch_bounds__(256) void k_final(const float* __restrict__ latpart,
    const float* __restrict__ f1w, const float* __restrict__ f1b,
    const float* __restrict__ f2w, const float* __restrict__ f2b,
    float* __restrict__ outp) {
  __shared__ float ls[256];
  __shared__ float hb[2048];
  int t = threadIdx.x;
  {
    int b = t >> 6, z = t & 63;
    float s = 0.f;
    for (int c = 0; c < 64; ++c) s += latpart[(b * 64 + c) * 64 + z];
    ls[t] = s;
    outp[4 + t] = s;  // lat_sum output (fp32)
  }
  __syncthreads();
  for (int rep = 0; rep < 8; ++rep) {
    int idx = rep * 256 + t;
    int b = idx >> 9, k = idx & 511;
    float acc = f1b[k];
    for (int z = 0; z < 64; ++z) acc += ls[b * 64 + z] * f1w[z * 512 + k];
    hb[idx] = tanh_fast(acc);
  }
  __syncthreads();
  {
    int b = t >> 6, lane = t & 63;
    float acc = 0.f;
#pragma unroll
    for (int u = 0; u < 8; ++u) acc += hb[b * 512 + lane + u * 64] * f2w[lane + u * 64];
#pragma unroll
    for (int off = 32; off > 0; off >>= 1) acc += __shfl_xor(acc, off, 64);
    if (lane == 0) outp[b] = acc + f2b[0];  // predict output (fp32)
  }
}

extern "C" void kernel_launch(void* const* d_in, const int* in_sizes, int n_in,
                              void* d_out, int out_size, void* d_ws, size_t ws_size,
                              hipStream_t stream) {
  const float* adj       = (const float*)d_in[0];
  const float* node_feat = (const float*)d_in[1];
  const float* edge_feat = (const float*)d_in[2];
  const float* nf1_w = (const float*)d_in[3];
  const float* nf1_b = (const float*)d_in[4];
  const float* nf2_w = (const float*)d_in[5];
  const float* nf2_b = (const float*)d_in[6];
  const float* ef1_w = (const float*)d_in[7];
  const float* ef1_b = (const float*)d_in[8];
  const float* ef2_w = (const float*)d_in[9];
  const float* ef2_b = (const float*)d_in[10];
  const float* gcn_w = (const float*)d_in[11];
  const float* vn1_w = (const float*)d_in[12];
  const float* vn1_b = (const float*)d_in[13];
  const float* vn1_g = (const float*)d_in[14];
  const float* vn1_be = (const float*)d_in[15];
  const float* vn2_w = (const float*)d_in[16];
  const float* vn2_b = (const float*)d_in[17];
  const float* vn2_g = (const float*)d_in[18];
  const float* vn2_be = (const float*)d_in[19];
  const float* comb_w = (const float*)d_in[20];
  const float* comb_b = (const float*)d_in[21];
  const float* lat1_w = (const float*)d_in[22];
  const float* lat1_b = (const float*)d_in[23];
  const float* lat2_w = (const float*)d_in[24];
  const float* lat2_b = (const float*)d_in[25];
  const float* fc1_w = (const float*)d_in[26];
  const float* fc1_b = (const float*)d_in[27];
  const float* fc2_w = (const float*)d_in[28];
  const float* fc2_b = (const float*)d_in[29];

  // ---- workspace layout, ws_size-tiered e_sum precision ----
  const int use16 = (ws_size < (size_t)12 * 1024 * 1024) ? 1 : 0;
  char* p = (char*)d_ws;
  float* es32 = (float*)p;
  u16*   es16 = (u16*)p;
  size_t es_bytes = use16 ? (size_t)1048576 * 2 : (size_t)1048576 * 4;
  u16*   alls16  = (u16*)(p + es_bytes);      // 524288 u16
  float* hid     = (float*)(alls16 + 524288); // 131072 f32
  float* tmp     = hid + 131072;              // 131072 (gcn tmp, then gated)
  float* dinv    = tmp + 131072;              // 2048
  float* vnpart  = dinv + 2048;               // 16384
  float* vn      = vnpart + 16384;            // 256
  float* latpart = vn + 256;                  // 16384
  int*   cnt     = (int*)(latpart + 16384);   // 4

  k_edge<<<1024, 256, 0, stream>>>(edge_feat, ef1_w, ef1_b, ef2_w, ef2_b,
                                   es32, es16, use16);
  k_node_gcn<<<512, 256, 0, stream>>>(node_feat, nf1_w, nf1_b, nf2_w, nf2_b,
                                      gcn_w, hid, alls16, tmp);
  k_dinv<<<512, 256, 0, stream>>>(adj, dinv, cnt);
  for (int l = 0; l < 3; ++l) {
    k_adjmm<0><<<256, 256, 0, stream>>>(adj, es32, es16, use16, tmp, vn, dinv,
        hid, vnpart, cnt + l,
        vn1_w, vn1_b, vn1_g, vn1_be, vn2_w, vn2_b, vn2_g, vn2_be, vn, l);
    k_adjmm<1><<<256, 256, 0, stream>>>(adj, es32, es16, use16, hid, vn, dinv,
        tmp, vnpart, cnt + l,
        vn1_w, vn1_b, vn1_g, vn1_be, vn2_w, vn2_b, vn2_g, vn2_be, vn, l);
    k_comb_gcn<<<512, 256, 0, stream>>>(hid, tmp, vn, comb_w, comb_b,
        gcn_w + (l + 1) * 4096, alls16, tmp, l, (l < 2) ? 1 : 0);
  }
  k_lat<<<256, 256, 0, stream>>>(alls16, lat1_w, lat1_b, lat2_w, lat2_b, latpart);
  k_final<<<1, 256, 0, stream>>>(latpart, fc1_w, fc1_b, fc2_w, fc2_b, (float*)d_out);
}